// Round 7
// baseline (229.043 us; speedup 1.0000x reference)
//
#include <hip/hip_runtime.h>

#define TT 32   // atoms per tile

// ---------------- zero out output ----------------
__global__ void zero_kernel(float* __restrict__ p, int n) {
    int i = blockIdx.x * blockDim.x + threadIdx.x;
    if (i < n) p[i] = 0.f;
}

__device__ __forceinline__ float sigm(float z) { return 1.f / (1.f + expf(-z)); }

__device__ __forceinline__ float f4c(const float4& v, int i) {
    switch (i) { case 0: return v.x; case 1: return v.y; case 2: return v.z; default: return v.w; }
}

// ---------------- fused MLP forward + backward (tile GEMM) ----------------
// One block = one 32-atom tile, 512 threads (8 waves) -> ~4.9 waves/SIMD.
// Weights from GLOBAL (L1/L2-cached, off the LDS pipe). Activations in LDS,
// chunk-XOR swizzle key = row&7.
__global__ __launch_bounds__(512, 4) void mlp_fwd_bwd(
    const float* __restrict__ x,
    const float* __restrict__ W1, const float* __restrict__ b1,
    const float* __restrict__ W2, const float* __restrict__ b2,
    const float* __restrict__ W3, const float* __restrict__ b3,
    const int* __restrict__ indices,
    float* __restrict__ energy_out, float* __restrict__ dEdD, int natoms)
{
    __shared__ float h1s[TT * 128];  // 16 KB: h1, later dz1 in-place
    __shared__ float Ss[TT * 128];   // 16 KB: xs (stride 64), later g2 (stride 128)

    const int tid = threadIdx.x;
    const int jb  = tid & 15;    // 8-wide output block
    const int al  = tid >> 4;    // atom 0..31
    const int a0  = blockIdx.x * TT;
    const int j0  = jb * 8;
    const int keyA = al & 7;

    // per-thread bias / W3 fragments (8 j's)
    float bb1[8], bb2[8], ww3[8];
    {
        float4 t0 = *(const float4*)(b1 + j0), t1 = *(const float4*)(b1 + j0 + 4);
        float4 u0 = *(const float4*)(b2 + j0), u1 = *(const float4*)(b2 + j0 + 4);
        float4 v0 = *(const float4*)(W3 + j0), v1 = *(const float4*)(W3 + j0 + 4);
        #pragma unroll
        for (int q = 0; q < 4; ++q) {
            bb1[q] = f4c(t0, q); bb1[4+q] = f4c(t1, q);
            bb2[q] = f4c(u0, q); bb2[4+q] = f4c(u1, q);
            ww3[q] = f4c(v0, q); ww3[4+q] = f4c(v1, q);
        }
    }
    const float b3v = b3[0];

    // ---- stage x tile into Ss (row stride 64 = 16 chunks), swizzled ----
    {
        int r = tid >> 4, c4 = tid & 15;
        int a = a0 + r;
        float4 v = make_float4(0.f, 0.f, 0.f, 0.f);
        if (a < natoms) v = *(const float4*)(x + (size_t)a * 64 + c4 * 4);
        *(float4*)(Ss + r * 64 + ((c4 ^ (r & 7)) << 2)) = v;
    }
    __syncthreads();

    // ---- layer 1: z1[al][j] = b1 + sum_d xs[al][d] * W1[d][j] ----
    float acc[8];
    #pragma unroll
    for (int q = 0; q < 8; ++q) acc[q] = bb1[q];

    #pragma unroll 4
    for (int d0 = 0; d0 < 64; d0 += 4) {
        const float4 xa = *(const float4*)(Ss + al * 64 + (((d0 >> 2) ^ keyA) << 2));
        float4 wv[4][2];
        #pragma unroll
        for (int d = 0; d < 4; ++d) {
            const float* wp = W1 + (size_t)(d0 + d) * 128 + j0;
            wv[d][0] = *(const float4*)(wp);
            wv[d][1] = *(const float4*)(wp + 4);
        }
        #pragma unroll
        for (int d = 0; d < 4; ++d) {
            const float xv = f4c(xa, d);
            #pragma unroll
            for (int q = 0; q < 4; ++q) {
                acc[q]     += xv * f4c(wv[d][0], q);
                acc[4 + q] += xv * f4c(wv[d][1], q);
            }
        }
    }
    {
        float4 h0, h1v;
        h0.x = sigm(acc[0]); h0.y = sigm(acc[1]); h0.z = sigm(acc[2]); h0.w = sigm(acc[3]);
        h1v.x = sigm(acc[4]); h1v.y = sigm(acc[5]); h1v.z = sigm(acc[6]); h1v.w = sigm(acc[7]);
        *(float4*)(h1s + al * 128 + (((2 * jb) ^ keyA) << 2)) = h0;
        *(float4*)(h1s + al * 128 + (((2 * jb + 1) ^ keyA) << 2)) = h1v;
    }
    __syncthreads();

    // ---- layer 2: z2[al][j] = b2 + sum_k h1[al][k] * W2[k][j] ----
    #pragma unroll
    for (int q = 0; q < 8; ++q) acc[q] = bb2[q];

    #pragma unroll 4
    for (int k0 = 0; k0 < 128; k0 += 4) {
        const float4 ha = *(const float4*)(h1s + al * 128 + (((k0 >> 2) ^ keyA) << 2));
        float4 wv[4][2];
        #pragma unroll
        for (int d = 0; d < 4; ++d) {
            const float* wp = W2 + (size_t)(k0 + d) * 128 + j0;
            wv[d][0] = *(const float4*)(wp);
            wv[d][1] = *(const float4*)(wp + 4);
        }
        #pragma unroll
        for (int d = 0; d < 4; ++d) {
            const float hv = f4c(ha, d);
            #pragma unroll
            for (int q = 0; q < 4; ++q) {
                acc[q]     += hv * f4c(wv[d][0], q);
                acc[4 + q] += hv * f4c(wv[d][1], q);
            }
        }
    }
    // h2, energy partial, g2 -> Ss (stride 128, swizzled)
    {
        float h2v[8];
        float e = 0.f;
        #pragma unroll
        for (int q = 0; q < 8; ++q) { h2v[q] = sigm(acc[q]); e += h2v[q] * ww3[q]; }
        e += __shfl_xor(e, 1); e += __shfl_xor(e, 2);
        e += __shfl_xor(e, 4); e += __shfl_xor(e, 8);
        if (jb == 0) {
            int a = a0 + al;
            if (a < natoms) atomicAdd(&energy_out[indices[a]], e + b3v);
        }
        float4 g0, g1;
        g0.x = ww3[0] * h2v[0] * (1.f - h2v[0]);
        g0.y = ww3[1] * h2v[1] * (1.f - h2v[1]);
        g0.z = ww3[2] * h2v[2] * (1.f - h2v[2]);
        g0.w = ww3[3] * h2v[3] * (1.f - h2v[3]);
        g1.x = ww3[4] * h2v[4] * (1.f - h2v[4]);
        g1.y = ww3[5] * h2v[5] * (1.f - h2v[5]);
        g1.z = ww3[6] * h2v[6] * (1.f - h2v[6]);
        g1.w = ww3[7] * h2v[7] * (1.f - h2v[7]);
        *(float4*)(Ss + al * 128 + (((2 * jb) ^ keyA) << 2)) = g0;
        *(float4*)(Ss + al * 128 + (((2 * jb + 1) ^ keyA) << 2)) = g1;
    }
    __syncthreads();

    // ---- dh1[m][k] = sum_j g2[m][j] * W2[k][j]; dz1 = dh1*h1*(1-h1) in-place ----
    {
        const int m  = tid & 31;          // atom
        const int kb = tid >> 5;          // 8-wide k-block (coalesced W2 rows)
        const int k0b = kb * 8;
        const int keyM = m & 7;
        float acc2[8];
        #pragma unroll
        for (int q = 0; q < 8; ++q) acc2[q] = 0.f;

        #pragma unroll 4
        for (int jj = 0; jj < 128; jj += 4) {
            const float4 ga = *(const float4*)(Ss + m * 128 + (((jj >> 2) ^ keyM) << 2));
            float4 wv[8];
            #pragma unroll
            for (int q = 0; q < 8; ++q)
                wv[q] = *(const float4*)(W2 + (size_t)(k0b + q) * 128 + jj);
            #pragma unroll
            for (int q = 0; q < 8; ++q)
                #pragma unroll
                for (int d = 0; d < 4; ++d)
                    acc2[q] += f4c(ga, d) * f4c(wv[q], d);
        }
        float* pA = h1s + m * 128 + (((2 * kb) ^ keyM) << 2);
        float* pB = h1s + m * 128 + (((2 * kb + 1) ^ keyM) << 2);
        float4 hA = *(float4*)pA, hB = *(float4*)pB;
        float4 zA, zB;
        zA.x = acc2[0] * hA.x * (1.f - hA.x);
        zA.y = acc2[1] * hA.y * (1.f - hA.y);
        zA.z = acc2[2] * hA.z * (1.f - hA.z);
        zA.w = acc2[3] * hA.w * (1.f - hA.w);
        zB.x = acc2[4] * hB.x * (1.f - hB.x);
        zB.y = acc2[5] * hB.y * (1.f - hB.y);
        zB.z = acc2[6] * hB.z * (1.f - hB.z);
        zB.w = acc2[7] * hB.w * (1.f - hB.w);
        *(float4*)pA = zA; *(float4*)pB = zB;
    }
    __syncthreads();

    // ---- dEdD[m][d] = sum_k dz1[m][k] * W1[d][k] ----
    {
        const int m  = tid & 31;          // atom
        const int db = tid >> 5;          // 4-wide d-block (coalesced W1 rows)
        const int d0b = db * 4;
        const int keyM = m & 7;
        float acc3[4];
        #pragma unroll
        for (int q = 0; q < 4; ++q) acc3[q] = 0.f;

        #pragma unroll 4
        for (int k0 = 0; k0 < 128; k0 += 4) {
            const float4 za = *(const float4*)(h1s + m * 128 + (((k0 >> 2) ^ keyM) << 2));
            float4 wv[4];
            #pragma unroll
            for (int q = 0; q < 4; ++q)
                wv[q] = *(const float4*)(W1 + (size_t)(d0b + q) * 128 + k0);
            #pragma unroll
            for (int q = 0; q < 4; ++q)
                #pragma unroll
                for (int d = 0; d < 4; ++d)
                    acc3[q] += f4c(za, d) * f4c(wv[q], d);
        }
        int a = a0 + m;
        if (a < natoms) {
            float4 o; o.x = acc3[0]; o.y = acc3[1]; o.z = acc3[2]; o.w = acc3[3];
            *(float4*)(dEdD + (size_t)a * 64 + d0b) = o;
        }
    }
}

// ---------------- force accumulation ----------------
// 16 lanes per row, 4 rows per wave. xd via PLAIN cached loads (R6 lesson:
// nt/no-allocate forfeits the ~256MB LLC retention of the 307MB xd stream
// across replays). dEdD gathers from L2/LLC. One atomicAdd per row.
__global__ __launch_bounds__(256) void force_kernel(
    const float* __restrict__ xd,
    const int* __restrict__ unique_i, const int* __restrict__ unique_j,
    const float* __restrict__ dEdD,
    float* __restrict__ forces, int nderiv)
{
    const int tid = threadIdx.x;
    const int lane = tid & 63;
    const int wib = tid >> 6;
    const int gwave = blockIdx.x * 4 + wib;
    const int nwaves = gridDim.x * 4;
    const int sub = lane >> 4;
    const int t = lane & 15;
    const int ngroups = (nderiv + 3) >> 2;

    for (int g = gwave; g < ngroups; g += nwaves) {
        const int r = g * 4 + sub;
        float p = 0.f;
        int jdst = 0, ax = 0;
        const bool valid = (r < nderiv);
        if (valid) {
            const int ai = unique_i[r];
            const float4 v = ((const float4*)(xd   + (size_t)r  * 64))[t];
            const float4 w = ((const float4*)(dEdD + (size_t)ai * 64))[t];
            p = v.x * w.x + v.y * w.y + v.z * w.z + v.w * w.w;
            jdst = unique_j[r];
            ax = r % 3;   // axis = tile([0,1,2]) by construction
        }
        p += __shfl_xor(p, 1);
        p += __shfl_xor(p, 2);
        p += __shfl_xor(p, 4);
        p += __shfl_xor(p, 8);
        if (t == 0 && valid) atomicAdd(&forces[jdst * 3 + ax], p);
    }
}

extern "C" void kernel_launch(void* const* d_in, const int* in_sizes, int n_in,
                              void* d_out, int out_size, void* d_ws, size_t ws_size,
                              hipStream_t stream) {
    const float* x        = (const float*)d_in[0];
    const float* xd       = (const float*)d_in[1];
    const int*   indices  = (const int*)d_in[2];
    const int*   unique_i = (const int*)d_in[6];
    const int*   unique_j = (const int*)d_in[7];
    const float* W1       = (const float*)d_in[8];
    const float* b1       = (const float*)d_in[9];
    const float* W2       = (const float*)d_in[10];
    const float* b2       = (const float*)d_in[11];
    const float* W3       = (const float*)d_in[12];
    const float* b3       = (const float*)d_in[13];

    const int natoms = in_sizes[2];
    const int nconf  = in_sizes[3];
    const int nderiv = in_sizes[6];

    float* out    = (float*)d_out;
    float* energy = out;
    float* forces = out + nconf;
    float* dEdD   = (float*)d_ws;

    const int ntiles = (natoms + TT - 1) / TT;

    zero_kernel<<<(out_size + 255) / 256, 256, 0, stream>>>(out, out_size);
    mlp_fwd_bwd<<<ntiles, 512, 0, stream>>>(x, W1, b1, W2, b2, W3, b3,
                                            indices, energy, dEdD, natoms);
    force_kernel<<<2048, 256, 0, stream>>>(xd, unique_i, unique_j, dEdD,
                                           forces, nderiv);
}

// Round 8
// 205.456 us; speedup vs baseline: 1.1148x; 1.1148x over previous
//
#include <hip/hip_runtime.h>

#define TT 64   // atoms per tile (A=4 atoms per thread, 256 threads)

// ---------------- zero out output ----------------
__global__ void zero_kernel(float* __restrict__ p, int n) {
    int i = blockIdx.x * blockDim.x + threadIdx.x;
    if (i < n) p[i] = 0.f;
}

__device__ __forceinline__ float sigm(float z) { return 1.f / (1.f + expf(-z)); }

__device__ __forceinline__ float f4c(const float4& v, int i) {
    switch (i) { case 0: return v.x; case 1: return v.y; case 2: return v.z; default: return v.w; }
}

// ---------------- fused MLP forward + backward (tile GEMM) ----------------
// One block = 64-atom tile, 256 threads. Each thread: 4 atoms x 8 outputs.
// R7 lesson: the kernel is L2-WEIGHT-TRAFFIC-bound. Traffic/block ~
// (#atom-groups)x96KB; A=4 halves traffic/atom vs R4's A=2.
// Weights from GLOBAL (L1/L2), activations in LDS (chunk-XOR swizzle, key=row&7).
__global__ __launch_bounds__(256, 2) void mlp_fwd_bwd(
    const float* __restrict__ x,
    const float* __restrict__ W1, const float* __restrict__ b1,
    const float* __restrict__ W2, const float* __restrict__ b2,
    const float* __restrict__ W3, const float* __restrict__ b3,
    const int* __restrict__ indices,
    float* __restrict__ energy_out, float* __restrict__ dEdD, int natoms)
{
    __shared__ float h1s[TT * 128];  // 32 KB: h1, later dz1 in-place
    __shared__ float Ss[TT * 128];   // 32 KB: xs (stride 64), later g2 (stride 128)

    const int tid = threadIdx.x;
    const int jb  = tid & 15;    // 8-wide output block
    const int ar  = tid >> 4;    // atom group 0..15 (atoms 4*ar .. 4*ar+3)
    const int a0  = blockIdx.x * TT;
    const int j0  = jb * 8;

    // per-thread bias / W3 fragments (8 j's)
    float bb1[8], bb2[8], ww3[8];
    {
        float4 t0 = *(const float4*)(b1 + j0), t1 = *(const float4*)(b1 + j0 + 4);
        float4 u0 = *(const float4*)(b2 + j0), u1 = *(const float4*)(b2 + j0 + 4);
        float4 v0 = *(const float4*)(W3 + j0), v1 = *(const float4*)(W3 + j0 + 4);
        #pragma unroll
        for (int q = 0; q < 4; ++q) {
            bb1[q] = f4c(t0, q); bb1[4+q] = f4c(t1, q);
            bb2[q] = f4c(u0, q); bb2[4+q] = f4c(u1, q);
            ww3[q] = f4c(v0, q); ww3[4+q] = f4c(v1, q);
        }
    }
    const float b3v = b3[0];

    // ---- stage x tile into Ss (row stride 64 = 16 chunks), swizzled ----
    #pragma unroll
    for (int p = 0; p < 4; ++p) {
        int idx = tid + p * 256;          // 1024 chunks = 64 rows x 16
        int r = idx >> 4, c4 = idx & 15;
        int a = a0 + r;
        float4 v = make_float4(0.f, 0.f, 0.f, 0.f);
        if (a < natoms) v = *(const float4*)(x + (size_t)a * 64 + c4 * 4);
        *(float4*)(Ss + r * 64 + ((c4 ^ (r & 7)) << 2)) = v;
    }
    __syncthreads();

    // ---- layer 1: z1[a][j] = b1 + sum_d xs[a][d] * W1[d][j] ----
    float acc[4][8];
    #pragma unroll
    for (int i = 0; i < 4; ++i)
        #pragma unroll
        for (int q = 0; q < 8; ++q) acc[i][q] = bb1[q];

    #pragma unroll 2
    for (int d0 = 0; d0 < 64; d0 += 4) {
        float4 xa[4];
        #pragma unroll
        for (int i = 0; i < 4; ++i) {
            int r = 4 * ar + i;
            xa[i] = *(const float4*)(Ss + r * 64 + (((d0 >> 2) ^ (r & 7)) << 2));
        }
        float4 wv[4][2];
        #pragma unroll
        for (int d = 0; d < 4; ++d) {
            const float* wp = W1 + (size_t)(d0 + d) * 128 + j0;
            wv[d][0] = *(const float4*)(wp);
            wv[d][1] = *(const float4*)(wp + 4);
        }
        #pragma unroll
        for (int i = 0; i < 4; ++i)
            #pragma unroll
            for (int d = 0; d < 4; ++d) {
                const float xv = f4c(xa[i], d);
                #pragma unroll
                for (int q = 0; q < 4; ++q) {
                    acc[i][q]     += xv * f4c(wv[d][0], q);
                    acc[i][4 + q] += xv * f4c(wv[d][1], q);
                }
            }
    }
    #pragma unroll
    for (int i = 0; i < 4; ++i) {
        int r = 4 * ar + i, key = r & 7;
        float4 h0, h1v;
        h0.x = sigm(acc[i][0]); h0.y = sigm(acc[i][1]); h0.z = sigm(acc[i][2]); h0.w = sigm(acc[i][3]);
        h1v.x = sigm(acc[i][4]); h1v.y = sigm(acc[i][5]); h1v.z = sigm(acc[i][6]); h1v.w = sigm(acc[i][7]);
        *(float4*)(h1s + r * 128 + (((2 * jb) ^ key) << 2)) = h0;
        *(float4*)(h1s + r * 128 + (((2 * jb + 1) ^ key) << 2)) = h1v;
    }
    __syncthreads();

    // ---- layer 2: z2[a][j] = b2 + sum_k h1[a][k] * W2[k][j] ----
    #pragma unroll
    for (int i = 0; i < 4; ++i)
        #pragma unroll
        for (int q = 0; q < 8; ++q) acc[i][q] = bb2[q];

    #pragma unroll 2
    for (int k0 = 0; k0 < 128; k0 += 4) {
        float4 ha[4];
        #pragma unroll
        for (int i = 0; i < 4; ++i) {
            int r = 4 * ar + i;
            ha[i] = *(const float4*)(h1s + r * 128 + (((k0 >> 2) ^ (r & 7)) << 2));
        }
        float4 wv[4][2];
        #pragma unroll
        for (int d = 0; d < 4; ++d) {
            const float* wp = W2 + (size_t)(k0 + d) * 128 + j0;
            wv[d][0] = *(const float4*)(wp);
            wv[d][1] = *(const float4*)(wp + 4);
        }
        #pragma unroll
        for (int i = 0; i < 4; ++i)
            #pragma unroll
            for (int d = 0; d < 4; ++d) {
                const float hv = f4c(ha[i], d);
                #pragma unroll
                for (int q = 0; q < 4; ++q) {
                    acc[i][q]     += hv * f4c(wv[d][0], q);
                    acc[i][4 + q] += hv * f4c(wv[d][1], q);
                }
            }
    }
    // h2, energy partials, g2 -> Ss (stride 128, swizzled)
    #pragma unroll
    for (int i = 0; i < 4; ++i) {
        float h2v[8];
        float e = 0.f;
        #pragma unroll
        for (int q = 0; q < 8; ++q) { h2v[q] = sigm(acc[i][q]); e += h2v[q] * ww3[q]; }
        e += __shfl_xor(e, 1); e += __shfl_xor(e, 2);
        e += __shfl_xor(e, 4); e += __shfl_xor(e, 8);
        int r = 4 * ar + i, key = r & 7;
        if (jb == 0) {
            int a = a0 + r;
            if (a < natoms) atomicAdd(&energy_out[indices[a]], e + b3v);
        }
        float4 g0, g1;
        g0.x = ww3[0] * h2v[0] * (1.f - h2v[0]);
        g0.y = ww3[1] * h2v[1] * (1.f - h2v[1]);
        g0.z = ww3[2] * h2v[2] * (1.f - h2v[2]);
        g0.w = ww3[3] * h2v[3] * (1.f - h2v[3]);
        g1.x = ww3[4] * h2v[4] * (1.f - h2v[4]);
        g1.y = ww3[5] * h2v[5] * (1.f - h2v[5]);
        g1.z = ww3[6] * h2v[6] * (1.f - h2v[6]);
        g1.w = ww3[7] * h2v[7] * (1.f - h2v[7]);
        *(float4*)(Ss + r * 128 + (((2 * jb) ^ key) << 2)) = g0;
        *(float4*)(Ss + r * 128 + (((2 * jb + 1) ^ key) << 2)) = g1;
    }
    __syncthreads();

    // ---- dh1[m][k] = sum_j g2[m][j] * W2[k][j]; dz1 = dh1*h1*(1-h1) in-place ----
    {
        const int kb = tid & 15;          // 8-wide k-block (16 distinct weight lines/instr)
        const int mr = tid >> 4;          // atom group
        const int k0b = kb * 8;
        float acc2[4][8];
        #pragma unroll
        for (int i = 0; i < 4; ++i)
            #pragma unroll
            for (int q = 0; q < 8; ++q) acc2[i][q] = 0.f;

        #pragma unroll 2
        for (int jj = 0; jj < 128; jj += 4) {
            float4 ga[4];
            #pragma unroll
            for (int i = 0; i < 4; ++i) {
                int r = 4 * mr + i;
                ga[i] = *(const float4*)(Ss + r * 128 + (((jj >> 2) ^ (r & 7)) << 2));
            }
            float4 wv[8];
            #pragma unroll
            for (int q = 0; q < 8; ++q)
                wv[q] = *(const float4*)(W2 + (size_t)(k0b + q) * 128 + jj);
            #pragma unroll
            for (int i = 0; i < 4; ++i)
                #pragma unroll
                for (int q = 0; q < 8; ++q)
                    #pragma unroll
                    for (int d = 0; d < 4; ++d)
                        acc2[i][q] += f4c(ga[i], d) * f4c(wv[q], d);
        }
        #pragma unroll
        for (int i = 0; i < 4; ++i) {
            int r = 4 * mr + i, key = r & 7;
            float* pA = h1s + r * 128 + (((2 * kb) ^ key) << 2);
            float* pB = h1s + r * 128 + (((2 * kb + 1) ^ key) << 2);
            float4 hA = *(float4*)pA, hB = *(float4*)pB;
            float4 zA, zB;
            zA.x = acc2[i][0] * hA.x * (1.f - hA.x);
            zA.y = acc2[i][1] * hA.y * (1.f - hA.y);
            zA.z = acc2[i][2] * hA.z * (1.f - hA.z);
            zA.w = acc2[i][3] * hA.w * (1.f - hA.w);
            zB.x = acc2[i][4] * hB.x * (1.f - hB.x);
            zB.y = acc2[i][5] * hB.y * (1.f - hB.y);
            zB.z = acc2[i][6] * hB.z * (1.f - hB.z);
            zB.w = acc2[i][7] * hB.w * (1.f - hB.w);
            *(float4*)pA = zA; *(float4*)pB = zB;
        }
    }
    __syncthreads();

    // ---- dEdD[m][d] = sum_k dz1[m][k] * W1[d][k] ----
    {
        const int db = tid & 15;          // 4-wide d-block (16 distinct weight lines/instr)
        const int mr = tid >> 4;          // atom group
        const int d0b = db * 4;
        float acc3[4][4];
        #pragma unroll
        for (int i = 0; i < 4; ++i)
            #pragma unroll
            for (int q = 0; q < 4; ++q) acc3[i][q] = 0.f;

        #pragma unroll 2
        for (int k0 = 0; k0 < 128; k0 += 4) {
            float4 za[4];
            #pragma unroll
            for (int i = 0; i < 4; ++i) {
                int r = 4 * mr + i;
                za[i] = *(const float4*)(h1s + r * 128 + (((k0 >> 2) ^ (r & 7)) << 2));
            }
            float4 wv[4];
            #pragma unroll
            for (int q = 0; q < 4; ++q)
                wv[q] = *(const float4*)(W1 + (size_t)(d0b + q) * 128 + k0);
            #pragma unroll
            for (int i = 0; i < 4; ++i)
                #pragma unroll
                for (int q = 0; q < 4; ++q)
                    #pragma unroll
                    for (int d = 0; d < 4; ++d)
                        acc3[i][q] += f4c(za[i], d) * f4c(wv[q], d);
        }
        #pragma unroll
        for (int i = 0; i < 4; ++i) {
            int a = a0 + 4 * mr + i;
            if (a < natoms) {
                float4 o; o.x = acc3[i][0]; o.y = acc3[i][1]; o.z = acc3[i][2]; o.w = acc3[i][3];
                *(float4*)(dEdD + (size_t)a * 64 + d0b) = o;
            }
        }
    }
}

// ---------------- force accumulation ----------------
// 16 lanes per row, 4 rows per wave. xd plain cached float4 loads (nt proved
// neutral in R6/R7 A/B). dEdD gathers from L2/LLC. One atomicAdd per row.
__global__ __launch_bounds__(256) void force_kernel(
    const float* __restrict__ xd,
    const int* __restrict__ unique_i, const int* __restrict__ unique_j,
    const float* __restrict__ dEdD,
    float* __restrict__ forces, int nderiv)
{
    const int tid = threadIdx.x;
    const int lane = tid & 63;
    const int wib = tid >> 6;
    const int gwave = blockIdx.x * 4 + wib;
    const int nwaves = gridDim.x * 4;
    const int sub = lane >> 4;
    const int t = lane & 15;
    const int ngroups = (nderiv + 3) >> 2;

    for (int g = gwave; g < ngroups; g += nwaves) {
        const int r = g * 4 + sub;
        float p = 0.f;
        int jdst = 0, ax = 0;
        const bool valid = (r < nderiv);
        if (valid) {
            const int ai = unique_i[r];
            const float4 v = ((const float4*)(xd   + (size_t)r  * 64))[t];
            const float4 w = ((const float4*)(dEdD + (size_t)ai * 64))[t];
            p = v.x * w.x + v.y * w.y + v.z * w.z + v.w * w.w;
            jdst = unique_j[r];
            ax = r % 3;   // axis = tile([0,1,2]) by construction
        }
        p += __shfl_xor(p, 1);
        p += __shfl_xor(p, 2);
        p += __shfl_xor(p, 4);
        p += __shfl_xor(p, 8);
        if (t == 0 && valid) atomicAdd(&forces[jdst * 3 + ax], p);
    }
}

extern "C" void kernel_launch(void* const* d_in, const int* in_sizes, int n_in,
                              void* d_out, int out_size, void* d_ws, size_t ws_size,
                              hipStream_t stream) {
    const float* x        = (const float*)d_in[0];
    const float* xd       = (const float*)d_in[1];
    const int*   indices  = (const int*)d_in[2];
    const int*   unique_i = (const int*)d_in[6];
    const int*   unique_j = (const int*)d_in[7];
    const float* W1       = (const float*)d_in[8];
    const float* b1       = (const float*)d_in[9];
    const float* W2       = (const float*)d_in[10];
    const float* b2       = (const float*)d_in[11];
    const float* W3       = (const float*)d_in[12];
    const float* b3       = (const float*)d_in[13];

    const int natoms = in_sizes[2];
    const int nconf  = in_sizes[3];
    const int nderiv = in_sizes[6];

    float* out    = (float*)d_out;
    float* energy = out;
    float* forces = out + nconf;
    float* dEdD   = (float*)d_ws;

    const int ntiles = (natoms + TT - 1) / TT;

    zero_kernel<<<(out_size + 255) / 256, 256, 0, stream>>>(out, out_size);
    mlp_fwd_bwd<<<ntiles, 256, 0, stream>>>(x, W1, b1, W2, b2, W3, b3,
                                            indices, energy, dEdD, natoms);
    force_kernel<<<2048, 256, 0, stream>>>(xd, unique_i, unique_j, dEdD,
                                           forces, nderiv);
}

// Round 9
// 140.892 us; speedup vs baseline: 1.6257x; 1.4583x over previous
//
#include <hip/hip_runtime.h>

typedef float f32x4 __attribute__((ext_vector_type(4)));
typedef __bf16 bf16x8 __attribute__((ext_vector_type(8)));
typedef unsigned int u32x4 __attribute__((ext_vector_type(4)));

#define TT 32   // atoms per block tile

// packed bf16 weight planes in d_ws after dEdD (ushort element offsets)
#define PW1_HI   0
#define PW1_LO   8192
#define PW2_HI   16384
#define PW2_LO   32768
#define PW2T_HI  49152
#define PW2T_LO  65536
#define PW1T_HI  81920
#define PW1T_LO  90112
#define PW_SLOTS 49152

__global__ void zero_kernel(float* __restrict__ p, int n) {
    int i = blockIdx.x * blockDim.x + threadIdx.x;
    if (i < n) p[i] = 0.f;
}

__device__ __forceinline__ void bf16split(float x, unsigned short& hi, unsigned short& lo) {
    unsigned u = __float_as_uint(x);
    unsigned r = (u + 0x7FFFu + ((u >> 16) & 1u)) >> 16;   // RNE to bf16
    hi = (unsigned short)r;
    float hf = __uint_as_float(r << 16);
    unsigned u2 = __float_as_uint(x - hf);                 // exact residual
    unsigned r2 = (u2 + 0x7FFFu + ((u2 >> 16) & 1u)) >> 16;
    lo = (unsigned short)r2;
}

// ---------------- weight pre-pack: fragment-ordered bf16 hi/lo planes ----------------
// B-fragment convention: elem(ks,ns,lane,j) = B[ks*32 + (lane>>4)*8 + j][ns*16 + (lane&15)]
// (any k-permutation cancels between A and B as long as both use this convention)
__global__ void pack_weights(const float* __restrict__ W1, const float* __restrict__ W2,
                             unsigned short* __restrict__ pw) {
    int s = blockIdx.x * blockDim.x + threadIdx.x;
    if (s >= PW_SLOTS) return;
    int slot, NS, hiOff, loOff; const float* src; bool tr;
    if (s < 8192)       { slot = s;         NS = 8; hiOff = PW1_HI;  loOff = PW1_LO;  tr = false; src = W1; }
    else if (s < 24576) { slot = s - 8192;  NS = 8; hiOff = PW2_HI;  loOff = PW2_LO;  tr = false; src = W2; }
    else if (s < 40960) { slot = s - 24576; NS = 8; hiOff = PW2T_HI; loOff = PW2T_LO; tr = true;  src = W2; }
    else                { slot = s - 40960; NS = 4; hiOff = PW1T_HI; loOff = PW1T_LO; tr = true;  src = W1; }
    int j = slot & 7, lane = (slot >> 3) & 63, rest = slot >> 9;
    int ns = rest % NS, ks = rest / NS;
    int k = ks * 32 + ((lane >> 4) & 3) * 8 + j;
    int n = ns * 16 + (lane & 15);
    float v = tr ? src[n * 128 + k] : src[k * 128 + n];
    unsigned short hi, lo;
    bf16split(v, hi, lo);
    pw[hiOff + slot] = hi;
    pw[loOff + slot] = lo;
}

// ---------------- fused MLP fwd+bwd via MFMA (bf16 hi/lo split, fp32-class accuracy) ----------------
// Block = 32 atoms, 4 waves. Wave w: msub = w>>1 (16-atom row tile), half = w&1 (column half).
// Per GEMM: A-frags from swizzled LDS (f32 -> bf16 hi/lo on the fly, hoisted over K),
// B-frags one coalesced 16B/lane load from the L2-resident packed planes.
// acc split: full = ahi*bhi + alo*bhi + ahi*blo  (lo*lo ~2^-18, dropped).
__global__ __launch_bounds__(256, 4) void mlp_mfma(
    const float* __restrict__ x,
    const float* __restrict__ b1, const float* __restrict__ b2,
    const float* __restrict__ W3, const float* __restrict__ b3,
    const int* __restrict__ indices,
    const unsigned short* __restrict__ pw,
    float* __restrict__ energy, float* __restrict__ dEdD, int natoms)
{
    __shared__ float xs[TT * 64];     // 8 KB, chunk-XOR swizzled (key = row&7)
    __shared__ float h1s[TT * 128];   // 16 KB: h1, overwritten in-place by dz1
    __shared__ float g2s[TT * 128];   // 16 KB

    const int tid = threadIdx.x;
    const int l   = tid & 63;
    const int w   = tid >> 6;
    const int col = l & 15;
    const int rg  = l >> 4;           // k-group (A/B) / row-group (D)
    const int msub = w >> 1;
    const int half = w & 1;
    const int a0 = blockIdx.x * TT;
    const int mrow = msub * 16 + col; // A-fragment row for this lane

    // ---- stage x (swizzled) ----
    #pragma unroll
    for (int p = 0; p < 2; ++p) {
        int idx = tid + p * 256;
        int r = idx >> 4, c = idx & 15;
        int a = a0 + r;
        f32x4 v = {0.f, 0.f, 0.f, 0.f};
        if (a < natoms) v = *(const f32x4*)(x + (size_t)a * 64 + c * 4);
        *(f32x4*)(xs + r * 64 + ((c ^ (r & 7)) << 2)) = v;
    }
    __syncthreads();

    auto loadA = [&](const float* buf, int stride, int kbase, bf16x8& ah, bf16x8& al) {
        int key = mrow & 7;
        int c0 = kbase >> 2;
        f32x4 f0 = *(const f32x4*)(buf + mrow * stride + (((c0    ) ^ key) << 2));
        f32x4 f1 = *(const f32x4*)(buf + mrow * stride + (((c0 + 1) ^ key) << 2));
        union { unsigned short u[8]; bf16x8 v; } H, L;
        #pragma unroll
        for (int i2 = 0; i2 < 4; ++i2) {
            bf16split(f0[i2], H.u[i2], L.u[i2]);
            bf16split(f1[i2], H.u[4 + i2], L.u[4 + i2]);
        }
        ah = H.v; al = L.v;
    };
    auto loadB = [&](int hiOff, int loOff, int NS, int ks, int nsub, bf16x8& bh, bf16x8& bl) {
        size_t idx = ((size_t)(ks * NS + nsub) * 64 + l) * 8;
        bh = __builtin_bit_cast(bf16x8, *(const u32x4*)(pw + hiOff + idx));
        bl = __builtin_bit_cast(bf16x8, *(const u32x4*)(pw + loOff + idx));
    };

    bf16x8 ah[4], al[4];

    // ---- GEMM1: z1 = X @ W1 + b1 ; h1 = sigm ----
    loadA(xs, 64, 0 * 32 + rg * 8, ah[0], al[0]);
    loadA(xs, 64, 1 * 32 + rg * 8, ah[1], al[1]);
    for (int ns = 0; ns < 4; ++ns) {
        int nsub = half * 4 + ns, n0 = nsub * 16;
        float bv = b1[n0 + col];
        f32x4 acc = {bv, bv, bv, bv};
        #pragma unroll
        for (int ks = 0; ks < 2; ++ks) {
            bf16x8 bh, bl; loadB(PW1_HI, PW1_LO, 8, ks, nsub, bh, bl);
            acc = __builtin_amdgcn_mfma_f32_16x16x32_bf16(ah[ks], bh, acc, 0, 0, 0);
            acc = __builtin_amdgcn_mfma_f32_16x16x32_bf16(al[ks], bh, acc, 0, 0, 0);
            acc = __builtin_amdgcn_mfma_f32_16x16x32_bf16(ah[ks], bl, acc, 0, 0, 0);
        }
        #pragma unroll
        for (int r2 = 0; r2 < 4; ++r2) {
            int m = msub * 16 + rg * 4 + r2, k = n0 + col;
            float h = 1.f / (1.f + expf(-acc[r2]));
            h1s[m * 128 + ((((k >> 2)) ^ (m & 7)) << 2) + (k & 3)] = h;
        }
    }
    __syncthreads();

    // ---- GEMM2: z2 = h1 @ W2 + b2 ; h2, energy, g2 ----
    #pragma unroll
    for (int ks = 0; ks < 4; ++ks) loadA(h1s, 128, ks * 32 + rg * 8, ah[ks], al[ks]);
    float e[4] = {0.f, 0.f, 0.f, 0.f};
    for (int ns = 0; ns < 4; ++ns) {
        int nsub = half * 4 + ns, n0 = nsub * 16;
        float bv = b2[n0 + col];
        f32x4 acc = {bv, bv, bv, bv};
        #pragma unroll
        for (int ks = 0; ks < 4; ++ks) {
            bf16x8 bh, bl; loadB(PW2_HI, PW2_LO, 8, ks, nsub, bh, bl);
            acc = __builtin_amdgcn_mfma_f32_16x16x32_bf16(ah[ks], bh, acc, 0, 0, 0);
            acc = __builtin_amdgcn_mfma_f32_16x16x32_bf16(al[ks], bh, acc, 0, 0, 0);
            acc = __builtin_amdgcn_mfma_f32_16x16x32_bf16(ah[ks], bl, acc, 0, 0, 0);
        }
        float w3v = W3[n0 + col];
        #pragma unroll
        for (int r2 = 0; r2 < 4; ++r2) {
            float h2 = 1.f / (1.f + expf(-acc[r2]));
            e[r2] += h2 * w3v;
            float g = w3v * h2 * (1.f - h2);
            int m = msub * 16 + rg * 4 + r2, k = n0 + col;
            g2s[m * 128 + ((((k >> 2)) ^ (m & 7)) << 2) + (k & 3)] = g;
        }
    }
    #pragma unroll
    for (int r2 = 0; r2 < 4; ++r2) {
        float v = e[r2];
        v += __shfl_xor(v, 1); v += __shfl_xor(v, 2);
        v += __shfl_xor(v, 4); v += __shfl_xor(v, 8);
        e[r2] = v;
    }
    if (col == 0) {
        float b3v = (half == 0) ? b3[0] : 0.f;
        #pragma unroll
        for (int r2 = 0; r2 < 4; ++r2) {
            int a = a0 + msub * 16 + rg * 4 + r2;
            if (a < natoms) atomicAdd(&energy[indices[a]], e[r2] + b3v);
        }
    }
    __syncthreads();

    // ---- GEMM3: dh1 = g2 @ W2^T ; dz1 = dh1*h1*(1-h1) in-place into h1s ----
    #pragma unroll
    for (int ks = 0; ks < 4; ++ks) loadA(g2s, 128, ks * 32 + rg * 8, ah[ks], al[ks]);
    for (int ns = 0; ns < 4; ++ns) {
        int nsub = half * 4 + ns, n0 = nsub * 16;
        f32x4 acc = {0.f, 0.f, 0.f, 0.f};
        #pragma unroll
        for (int ks = 0; ks < 4; ++ks) {
            bf16x8 bh, bl; loadB(PW2T_HI, PW2T_LO, 8, ks, nsub, bh, bl);
            acc = __builtin_amdgcn_mfma_f32_16x16x32_bf16(ah[ks], bh, acc, 0, 0, 0);
            acc = __builtin_amdgcn_mfma_f32_16x16x32_bf16(al[ks], bh, acc, 0, 0, 0);
            acc = __builtin_amdgcn_mfma_f32_16x16x32_bf16(ah[ks], bl, acc, 0, 0, 0);
        }
        #pragma unroll
        for (int r2 = 0; r2 < 4; ++r2) {
            int m = msub * 16 + rg * 4 + r2, k = n0 + col;
            int off = m * 128 + ((((k >> 2)) ^ (m & 7)) << 2) + (k & 3);
            float hv = h1s[off];
            h1s[off] = acc[r2] * hv * (1.f - hv);
        }
    }
    __syncthreads();

    // ---- GEMM4: dEdD = dz1 @ W1^T ----
    #pragma unroll
    for (int ks = 0; ks < 4; ++ks) loadA(h1s, 128, ks * 32 + rg * 8, ah[ks], al[ks]);
    for (int ns = 0; ns < 2; ++ns) {
        int nsub = half * 2 + ns, n0 = nsub * 16;
        f32x4 acc = {0.f, 0.f, 0.f, 0.f};
        #pragma unroll
        for (int ks = 0; ks < 4; ++ks) {
            bf16x8 bh, bl; loadB(PW1T_HI, PW1T_LO, 4, ks, nsub, bh, bl);
            acc = __builtin_amdgcn_mfma_f32_16x16x32_bf16(ah[ks], bh, acc, 0, 0, 0);
            acc = __builtin_amdgcn_mfma_f32_16x16x32_bf16(al[ks], bh, acc, 0, 0, 0);
            acc = __builtin_amdgcn_mfma_f32_16x16x32_bf16(ah[ks], bl, acc, 0, 0, 0);
        }
        #pragma unroll
        for (int r2 = 0; r2 < 4; ++r2) {
            int a = a0 + msub * 16 + rg * 4 + r2;
            if (a < natoms) dEdD[(size_t)a * 64 + n0 + col] = acc[r2];
        }
    }
}

// ---------------- force accumulation (unchanged, proven) ----------------
__global__ __launch_bounds__(256) void force_kernel(
    const float* __restrict__ xd,
    const int* __restrict__ unique_i, const int* __restrict__ unique_j,
    const float* __restrict__ dEdD,
    float* __restrict__ forces, int nderiv)
{
    const int tid = threadIdx.x;
    const int lane = tid & 63;
    const int wib = tid >> 6;
    const int gwave = blockIdx.x * 4 + wib;
    const int nwaves = gridDim.x * 4;
    const int sub = lane >> 4;
    const int t = lane & 15;
    const int ngroups = (nderiv + 3) >> 2;

    for (int g = gwave; g < ngroups; g += nwaves) {
        const int r = g * 4 + sub;
        float p = 0.f;
        int jdst = 0, ax = 0;
        const bool valid = (r < nderiv);
        if (valid) {
            const int ai = unique_i[r];
            const float4 v = ((const float4*)(xd   + (size_t)r  * 64))[t];
            const float4 wv = ((const float4*)(dEdD + (size_t)ai * 64))[t];
            p = v.x * wv.x + v.y * wv.y + v.z * wv.z + v.w * wv.w;
            jdst = unique_j[r];
            ax = r % 3;   // axis = tile([0,1,2]) by construction
        }
        p += __shfl_xor(p, 1);
        p += __shfl_xor(p, 2);
        p += __shfl_xor(p, 4);
        p += __shfl_xor(p, 8);
        if (t == 0 && valid) atomicAdd(&forces[jdst * 3 + ax], p);
    }
}

extern "C" void kernel_launch(void* const* d_in, const int* in_sizes, int n_in,
                              void* d_out, int out_size, void* d_ws, size_t ws_size,
                              hipStream_t stream) {
    const float* x        = (const float*)d_in[0];
    const float* xd       = (const float*)d_in[1];
    const int*   indices  = (const int*)d_in[2];
    const int*   unique_i = (const int*)d_in[6];
    const int*   unique_j = (const int*)d_in[7];
    const float* W1       = (const float*)d_in[8];
    const float* b1       = (const float*)d_in[9];
    const float* W2       = (const float*)d_in[10];
    const float* b2       = (const float*)d_in[11];
    const float* W3       = (const float*)d_in[12];
    const float* b3       = (const float*)d_in[13];

    const int natoms = in_sizes[2];
    const int nconf  = in_sizes[3];
    const int nderiv = in_sizes[6];

    float* out    = (float*)d_out;
    float* energy = out;
    float* forces = out + nconf;
    float* dEdD   = (float*)d_ws;
    unsigned short* pw = (unsigned short*)((char*)d_ws + (size_t)natoms * 64 * 4);

    const int ntiles = (natoms + TT - 1) / TT;

    zero_kernel<<<(out_size + 255) / 256, 256, 0, stream>>>(out, out_size);
    pack_weights<<<(PW_SLOTS + 255) / 256, 256, 0, stream>>>(W1, W2, pw);
    mlp_mfma<<<ntiles, 256, 0, stream>>>(x, b1, b2, W3, b3, indices, pw,
                                         energy, dEdD, natoms);
    force_kernel<<<2048, 256, 0, stream>>>(xd, unique_i, unique_j, dEdD,
                                           forces, nderiv);
}